// Round 1
// baseline (3428.216 us; speedup 1.0000x reference)
//
#include <hip/hip_runtime.h>
#include <cmath>

// Problem constants: B=64, L=512, H=64, 2H=128, VOC=32000, OUT=5
static constexpr int kB   = 64;
static constexpr int kL   = 512;
static constexpr int kH   = 64;
static constexpr int kH2  = 128;
static constexpr int kOut = 5;

// ---------------- embedding gather: nodes0[b,l,h] = embed[tokens[b,l], h] ----
__global__ void gather_k(const int* __restrict__ tok,
                         const float* __restrict__ embed,
                         float* __restrict__ out) {
  int idx = blockIdx.x * 256 + threadIdx.x;   // over B*L*H, exact multiple
  int bl = idx >> 6;                          // which token
  int h  = idx & 63;
  out[idx] = embed[tok[bl] * kH + h];
}

// ---------------- one tree level: out[m,i] = tanh(c^T V_i c + (W^T c)_i + b_i)
// c (128) = concat of children rows = contiguous 128 floats at in + m*128.
// Mapping: lane = node (64 nodes per block), wave handles NI consecutive i's,
// grid.y splits the i-dimension. V/W addresses are wave-uniform -> s_load.
template<int NI>
__global__ __launch_bounds__(256) void combine_k(
    const float* __restrict__ in, float* __restrict__ out,
    const float* __restrict__ V, const float* __restrict__ W,
    const float* __restrict__ bias, int Nout)
{
  __shared__ float c[64][129];                // +1 pad: (lane+q)%32 -> 2-way, free
  const int t    = threadIdx.x;
  const int lane = t & 63;
  const int w    = t >> 6;
  const long m0  = (long)blockIdx.x * 64;     // node tile base (M = 64*Nout)

  // cooperative stage: 64 nodes x 128 floats, coalesced float4
  const float4* src = (const float4*)(in + m0 * kH2);
  #pragma unroll
  for (int j = 0; j < 8; ++j) {
    int f = t + 256 * j;                      // 0..2047 float4s
    float4 v = src[f];
    int row = f >> 5;
    int col = (f & 31) << 2;
    float* dst = &c[row][col];
    dst[0] = v.x; dst[1] = v.y; dst[2] = v.z; dst[3] = v.w;
  }
  __syncthreads();

  int i0 = NI * (4 * (int)blockIdx.y + w);    // wave-uniform i base
  i0 = __builtin_amdgcn_readfirstlane(i0);    // force SGPR -> s_load for V/W
  const float* __restrict__ cr = &c[lane][0];

  float acc[NI], wacc[NI];
  #pragma unroll
  for (int k = 0; k < NI; ++k) { acc[k] = 0.f; wacc[k] = 0.f; }

  const float* __restrict__ Vb = V + (long)i0 * (kH2 * kH2);
  for (int p = 0; p < kH2; ++p) {
    const float* __restrict__ Vp = Vb + p * kH2;
    float s[NI];
    #pragma unroll
    for (int k = 0; k < NI; ++k) s[k] = 0.f;
    #pragma unroll 8
    for (int q = 0; q < kH2; ++q) {
      float cq = cr[q];                       // ds_read, amortized over NI FMAs
      #pragma unroll
      for (int k = 0; k < NI; ++k)
        s[k] = fmaf(Vp[k * (kH2 * kH2) + q], cq, s[k]);   // scalar V load
    }
    float cp = cr[p];
    #pragma unroll
    for (int k = 0; k < NI; ++k) acc[k] = fmaf(cp, s[k], acc[k]);
  }

  // Wx term (cheap: 128*NI MACs)
  #pragma unroll 16
  for (int p = 0; p < kH2; ++p) {
    float cp = cr[p];
    #pragma unroll
    for (int k = 0; k < NI; ++k)
      wacc[k] = fmaf(cp, W[p * kH + i0 + k], wacc[k]);
  }

  const long mg = m0 + lane;
  #pragma unroll
  for (int k = 0; k < NI; ++k) {
    float z = acc[k] + wacc[k] + bias[i0 + k];
    out[mg * kH + i0 + k] = tanhf(z);
  }
}

// ---------------- head: logits = root @ Wout + bout; log_softmax ------------
__global__ void head_k(const float* __restrict__ root,
                       const float* __restrict__ Wout,
                       const float* __restrict__ bout,
                       float* __restrict__ out) {
  int b = threadIdx.x;                        // 64 threads, one per batch row
  float l[kOut];
  #pragma unroll
  for (int o = 0; o < kOut; ++o) l[o] = bout[o];
  for (int h = 0; h < kH; ++h) {
    float r = root[b * kH + h];
    #pragma unroll
    for (int o = 0; o < kOut; ++o) l[o] = fmaf(r, Wout[h * kOut + o], l[o]);
  }
  float mx = l[0];
  #pragma unroll
  for (int o = 1; o < kOut; ++o) mx = fmaxf(mx, l[o]);
  float s = 0.f;
  #pragma unroll
  for (int o = 0; o < kOut; ++o) s += expf(l[o] - mx);
  float lse = logf(s);
  #pragma unroll
  for (int o = 0; o < kOut; ++o) out[b * kOut + o] = l[o] - mx - lse;
}

extern "C" void kernel_launch(void* const* d_in, const int* in_sizes, int n_in,
                              void* d_out, int out_size, void* d_ws, size_t ws_size,
                              hipStream_t stream) {
  const int*   tokens = (const int*)  d_in[0];
  const float* embed  = (const float*)d_in[1];
  const float* V      = (const float*)d_in[2];
  const float* W      = (const float*)d_in[3];
  const float* bias   = (const float*)d_in[4];
  const float* Wout   = (const float*)d_in[5];
  const float* bout   = (const float*)d_in[6];
  float* out = (float*)d_out;

  // ws layout: A = level buffer (8 MB), Bb = ping-pong buffer (4 MB). 12 MB total.
  float* A  = (float*)d_ws;
  float* Bb = A + (size_t)kB * kL * kH;       // after 2M floats

  gather_k<<<dim3(kB * kL * kH / 256), 256, 0, stream>>>(tokens, embed, A);

  const float* cur = A;
  float* nxt = Bb;
  for (int Nin = kL; Nin > 1; Nin >>= 1) {
    int Nout = Nin >> 1;                      // nodes per batch after combine
    if (Nout >= 64) {
      // big levels: NI=4 i's/wave, 4-way i-split -> Nout*4 blocks
      combine_k<4><<<dim3(Nout, 4), 256, 0, stream>>>(cur, nxt, V, W, bias, Nout);
    } else {
      // deep levels: NI=1 i/wave, 16-way i-split to cut serial latency
      combine_k<1><<<dim3(Nout, 16), 256, 0, stream>>>(cur, nxt, V, W, bias, Nout);
    }
    cur = nxt;
    nxt = (nxt == Bb) ? A : Bb;
  }
  // after 9 levels cur == Bb (odd count), holds root (B,1,H)
  head_k<<<1, 64, 0, stream>>>(cur, Wout, bout, out);
}

// Round 2
// 271.354 us; speedup vs baseline: 12.6338x; 12.6338x over previous
//
#include <hip/hip_runtime.h>
#include <cmath>

// B=64, L=512, H=64, 2H=128, OUT=5
static constexpr int kB = 64, kL = 512, kH = 64, kH2 = 128, kOut = 5;

typedef short bf16x8 __attribute__((ext_vector_type(8)));
typedef float f32x4  __attribute__((ext_vector_type(4)));

__device__ __forceinline__ unsigned short f2bf(float f) {
  unsigned u = __float_as_uint(f);
  unsigned r = (u + 0x7FFFu + ((u >> 16) & 1u)) >> 16;   // RNE
  return (unsigned short)r;
}

__device__ __forceinline__ void cvt8(const f32x4& v0, const f32x4& v1,
                                     bf16x8& hi, bf16x8& lo) {
  #pragma unroll
  for (int j = 0; j < 4; ++j) {
    unsigned short h0 = f2bf(v0[j]);
    unsigned short h1 = f2bf(v1[j]);
    hi[j]     = (short)h0;
    hi[j + 4] = (short)h1;
    lo[j]     = (short)f2bf(v0[j] - __uint_as_float(((unsigned)h0) << 16));
    lo[j + 4] = (short)f2bf(v1[j] - __uint_as_float(((unsigned)h1) << 16));
  }
}

// ---- prepass: V fp32 -> bf16 (row-major [i][p][q]); W -> Wt bf16 [i][p] ----
__global__ void prep_k(const float* __restrict__ V, const float* __restrict__ W,
                       unsigned short* __restrict__ vhi, unsigned short* __restrict__ wt) {
  int idx = blockIdx.x * 256 + threadIdx.x;
  if (idx < kH * kH2 * kH2) {
    vhi[idx] = f2bf(V[idx]);
  } else {
    int widx = idx - kH * kH2 * kH2;
    if (widx < kH * kH2) {
      int i = widx >> 7, p = widx & 127;
      wt[widx] = f2bf(W[p * kH + i]);      // Wt[i][p] = W[p][i]
    }
  }
}

// ---- fused combine level: out[m,i] = tanh(c_m^T V_i c_m + (W^T c_m)_i + b_i)
// MFMA orientation: D[p, m] = sum_q V_i[p,q] * C[m,q]  (A = V_i, B = C hi/lo)
// then R[m,i] = sum_p C[m,p] * D[p,m] via per-lane dot + xor16/xor32 butterfly.
template<bool FIRST>
__global__ __launch_bounds__(256) void combine2_k(
    const float* __restrict__ in, const int* __restrict__ tokens,
    const float* __restrict__ embed, const unsigned short* __restrict__ vhi,
    const unsigned short* __restrict__ wt, const float* __restrict__ bias,
    float* __restrict__ out, int M, int IS)
{
  __shared__ unsigned short Vs[kH2 * kH2];   // 32 KB, XOR-swizzled 16B chunks
  __shared__ float res[128 * 17];            // Wx+bias, then += xVx; pad 17

  const int t = threadIdx.x;
  const int lane = t & 63, w = t >> 6;
  const int c = lane & 15, q = lane >> 4;    // c = B-col (node), q = quad
  const int m0 = (int)blockIdx.x * 128;
  const int i0 = (int)blockIdx.y * IS;
  const int Mrows = (M < 128) ? M : 128;
  const bool has_rows = (w * 32) < Mrows;

  bf16x8 bh[2][4], bl[2][4];   // C hi/lo B-fragments, [mtile][kstep]
  f32x4  Cred[2][8];           // C fp32 for the p-reduction, [mtile][ptile]

  if (has_rows) {
    #pragma unroll
    for (int mt = 0; mt < 2; ++mt) {
      int m = m0 + w * 32 + mt * 16 + c;     // this lane's node row
      const float* crow = nullptr;
      int tokA = 0, tokB = 0;
      if (FIRST) {                           // level 1: gather from embed
        int b = m >> 8, j = m & 255;         // Nout=256
        tokA = tokens[b * kL + 2 * j];
        tokB = tokens[b * kL + 2 * j + 1];
      } else {
        crow = in + (size_t)m * kH2;
      }
      #pragma unroll
      for (int ks = 0; ks < 4; ++ks) {       // B-frag: 8 contiguous q at lane's m
        int q0 = ks * 32 + q * 8;
        const float* src = FIRST
            ? (embed + (size_t)(q0 < 64 ? tokA : tokB) * kH + (q0 & 63))
            : (crow + q0);
        f32x4 v0 = *(const f32x4*)src;
        f32x4 v1 = *(const f32x4*)(src + 4);
        cvt8(v0, v1, bh[mt][ks], bl[mt][ks]);
      }
      #pragma unroll
      for (int pt = 0; pt < 8; ++pt) {       // reduction copy: C[m, pt*16+q*4 ..+4]
        int p0 = pt * 16 + q * 4;
        const float* src = FIRST
            ? (embed + (size_t)(p0 < 64 ? tokA : tokB) * kH + (p0 & 63))
            : (crow + p0);
        Cred[mt][pt] = *(const f32x4*)src;
      }
    }
    // Wx GEMM: D'[i, m] = sum_p Wt[i,p] * C[m,p]; res init = Wx + bias
    {
      int irow = i0 + c; if (irow > 63) irow = 63;
      f32x4 ah0 = {0.f,0.f,0.f,0.f}, al0 = ah0, ah1 = ah0, al1 = ah0;
      #pragma unroll
      for (int ks = 0; ks < 4; ++ks) {
        bf16x8 a = *(const bf16x8*)(wt + (size_t)irow * kH2 + ks * 32 + q * 8);
        ah0 = __builtin_amdgcn_mfma_f32_16x16x32_bf16(a, bh[0][ks], ah0, 0, 0, 0);
        al0 = __builtin_amdgcn_mfma_f32_16x16x32_bf16(a, bl[0][ks], al0, 0, 0, 0);
        ah1 = __builtin_amdgcn_mfma_f32_16x16x32_bf16(a, bh[1][ks], ah1, 0, 0, 0);
        al1 = __builtin_amdgcn_mfma_f32_16x16x32_bf16(a, bl[1][ks], al1, 0, 0, 0);
      }
      #pragma unroll
      for (int reg = 0; reg < 4; ++reg) {
        int ii = q * 4 + reg;                // i-row within tile
        if (ii < IS) {
          float bv = bias[i0 + ii];
          res[(w * 32 + c) * 17 + ii]      = ah0[reg] + al0[reg] + bv;
          res[(w * 32 + 16 + c) * 17 + ii] = ah1[reg] + al1[reg] + bv;
        }
      }
    }
  }

  // V_i staging: XOR-chunk swizzle, global_load_lds width=16, wave-uniform dest
  auto stageV = [&](int i) {
    const unsigned short* vsrc = vhi + (size_t)i * (kH2 * kH2);
    #pragma unroll
    for (int r = 0; r < 8; ++r) {
      int chunk = w * 512 + r * 64 + lane;   // physical 16B chunk in LDS
      int p  = chunk >> 4;
      int pc = chunk & 15;
      int cc = pc ^ (p & 7);                 // logical chunk in V row p
      const unsigned short* g = vsrc + p * kH2 + cc * 8;
      __builtin_amdgcn_global_load_lds(
          (const __attribute__((address_space(1))) unsigned int*)g,
          (__attribute__((address_space(3))) unsigned int*)
              ((char*)&Vs[0] + (size_t)(w * 512 + r * 64) * 16),
          16, 0, 0);
    }
  };

  stageV(i0);
  __syncthreads();

  for (int ic = 0; ic < IS; ++ic) {
    if (has_rows) {
      float g0 = 0.f, g1 = 0.f;
      for (int pt = 0; pt < 8; ++pt) {
        f32x4 a0 = {0.f,0.f,0.f,0.f}, a1 = a0, a2 = a0, a3 = a0;
        #pragma unroll
        for (int ks = 0; ks < 4; ++ks) {
          int p  = pt * 16 + c;              // A-frag: V row p, 8 bf16 at q-chunk
          int cc = (ks * 4 + q) ^ (p & 7);   // swizzled chunk
          bf16x8 vf = *(const bf16x8*)((const char*)&Vs[0] + (size_t)p * 256 + cc * 16);
          a0 = __builtin_amdgcn_mfma_f32_16x16x32_bf16(vf, bh[0][ks], a0, 0, 0, 0);
          a1 = __builtin_amdgcn_mfma_f32_16x16x32_bf16(vf, bl[0][ks], a1, 0, 0, 0);
          a2 = __builtin_amdgcn_mfma_f32_16x16x32_bf16(vf, bh[1][ks], a2, 0, 0, 0);
          a3 = __builtin_amdgcn_mfma_f32_16x16x32_bf16(vf, bl[1][ks], a3, 0, 0, 0);
        }
        f32x4 d0 = a0 + a1, d1 = a2 + a3;    // hi+lo
        f32x4 cr0 = Cred[0][pt], cr1 = Cred[1][pt];
        g0 = fmaf(cr0[0], d0[0], g0); g0 = fmaf(cr0[1], d0[1], g0);
        g0 = fmaf(cr0[2], d0[2], g0); g0 = fmaf(cr0[3], d0[3], g0);
        g1 = fmaf(cr1[0], d1[0], g1); g1 = fmaf(cr1[1], d1[1], g1);
        g1 = fmaf(cr1[2], d1[2], g1); g1 = fmaf(cr1[3], d1[3], g1);
      }
      // sum over quads (p covers all 128 after this)
      g0 += __shfl_xor(g0, 16); g0 += __shfl_xor(g0, 32);
      g1 += __shfl_xor(g1, 16); g1 += __shfl_xor(g1, 32);
      if (q == 0)      res[(w * 32 + c) * 17 + ic]      += g0;
      else if (q == 1) res[(w * 32 + 16 + c) * 17 + ic] += g1;
    }
    __syncthreads();                          // V reads + res writes done
    if (ic + 1 < IS) { stageV(i0 + ic + 1); __syncthreads(); }
  }

  // epilogue: tanh + store (coalesced over i within row)
  const int sh = __builtin_ctz(IS);
  for (int idx = t; idx < Mrows * IS; idx += 256) {
    int m = idx >> sh, ii = idx & (IS - 1);
    out[(size_t)(m0 + m) * kH + i0 + ii] = tanhf(res[m * 17 + ii]);
  }
}

// ---- head: logits = root @ Wout + bout; log_softmax ----
__global__ void head_k(const float* __restrict__ root,
                       const float* __restrict__ Wout,
                       const float* __restrict__ bout,
                       float* __restrict__ out) {
  int b = threadIdx.x;
  float l[kOut];
  #pragma unroll
  for (int o = 0; o < kOut; ++o) l[o] = bout[o];
  for (int h = 0; h < kH; ++h) {
    float r = root[b * kH + h];
    #pragma unroll
    for (int o = 0; o < kOut; ++o) l[o] = fmaf(r, Wout[h * kOut + o], l[o]);
  }
  float mx = l[0];
  #pragma unroll
  for (int o = 1; o < kOut; ++o) mx = fmaxf(mx, l[o]);
  float s = 0.f;
  #pragma unroll
  for (int o = 0; o < kOut; ++o) s += expf(l[o] - mx);
  float lse = logf(s);
  #pragma unroll
  for (int o = 0; o < kOut; ++o) out[b * kOut + o] = l[o] - mx - lse;
}

extern "C" void kernel_launch(void* const* d_in, const int* in_sizes, int n_in,
                              void* d_out, int out_size, void* d_ws, size_t ws_size,
                              hipStream_t stream) {
  const int*   tokens = (const int*)  d_in[0];
  const float* embed  = (const float*)d_in[1];
  const float* V      = (const float*)d_in[2];
  const float* W      = (const float*)d_in[3];
  const float* bias   = (const float*)d_in[4];
  const float* Wout   = (const float*)d_in[5];
  const float* bout   = (const float*)d_in[6];
  float* out = (float*)d_out;

  // ws layout: vhi 2MB | wt 16KB | bufA 4MB | bufB 2MB  (~8.3 MB total)
  char* ws = (char*)d_ws;
  unsigned short* vhi = (unsigned short*)ws;
  unsigned short* wt  = (unsigned short*)(ws + 2097152);
  float* bufA = (float*)(ws + 2097152 + 16384);
  float* bufB = (float*)(ws + 2097152 + 16384 + 4194304);

  int nprep = kH * kH2 * kH2 + kH * kH2;
  prep_k<<<dim3((nprep + 255) / 256), 256, 0, stream>>>(V, W, vhi, wt);

  const float* cur = nullptr;
  float* nxt = bufA;
  bool first = true;
  for (int Nout = 256; Nout >= 1; Nout >>= 1) {
    int M = kB * Nout;
    int gx = (M + 127) / 128;
    int IS = gx / 8; if (IS < 1) IS = 1; if (IS > 16) IS = 16;
    dim3 grid(gx, 64 / IS);
    if (first)
      combine2_k<true ><<<grid, 256, 0, stream>>>(nullptr, tokens, embed, vhi, wt, bias, nxt, M, IS);
    else
      combine2_k<false><<<grid, 256, 0, stream>>>(cur, nullptr, nullptr, vhi, wt, bias, nxt, M, IS);
    first = false;
    cur = nxt;
    nxt = (nxt == bufA) ? bufB : bufA;
  }
  head_k<<<1, 64, 0, stream>>>(cur, Wout, bout, out);   // cur == bufA (9 levels)
}